// Round 3
// baseline (4128.260 us; speedup 1.0000x reference)
//
#include <hip/hip_runtime.h>

#define BLOCK      256
#define DC         8          // db chunks (grid.y)
#define CHUNKPTS   2048       // db points per block
#define STAGEPTS   512        // db points per LDS stage
#define STAGEBYTES 16384      // STAGEPTS * 32 B
#define NSTAGE     4          // CHUNKPTS / STAGEPTS
#define NQ         16384
#define QPW        128        // queries per wave = 4 MFMA A-tiles

typedef _Float16 f16;
typedef __attribute__((ext_vector_type(8)))  _Float16 f16x8;
typedef __attribute__((ext_vector_type(16))) float    f32x16;

union Pack { f16 h[16]; uint4 u[2]; };
union U8   { uint4 u; f16x8 v; };

__device__ __forceinline__ void split(float v, f16& h, f16& l) {
    h = (f16)v;
    l = (f16)(v - (float)h);
}

// db-side K-row: B[k] = {ph(3), pl(3), ph(3), pl(3), n2h, n2l, 0, 0}
__device__ __forceinline__ Pack pack_db(float x, float y, float z) {
    f16 hx, lx, hy, ly, hz, lz, nh, nl;
    split(x, hx, lx); split(y, hy, ly); split(z, hz, lz);
    float n2 = fmaf(x, x, fmaf(y, y, z * z));
    split(n2, nh, nl);
    Pack p;
    p.h[0] = hx;  p.h[1] = hy;  p.h[2] = hz;
    p.h[3] = lx;  p.h[4] = ly;  p.h[5] = lz;
    p.h[6] = hx;  p.h[7] = hy;  p.h[8] = hz;
    p.h[9] = lx;  p.h[10] = ly; p.h[11] = lz;
    p.h[12] = nh; p.h[13] = nl; p.h[14] = (f16)0.f; p.h[15] = (f16)0.f;
    return p;
}

// query-side K-row: A[k] = {-2qh(3), -2qh(3), -2ql(3), -2ql(3), 1, 1, 0, 0}
// pairing with B gives  -2*(qh+ql).(ph+pl) + |p|^2  to ~2^-22 relative.
__device__ __forceinline__ Pack pack_q(float x, float y, float z) {
    f16 hx, lx, hy, ly, hz, lz;
    split(-2.f * x, hx, lx); split(-2.f * y, hy, ly); split(-2.f * z, hz, lz);
    Pack p;
    p.h[0] = hx; p.h[1] = hy; p.h[2] = hz;
    p.h[3] = hx; p.h[4] = hy; p.h[5] = hz;
    p.h[6] = lx; p.h[7] = ly; p.h[8] = lz;
    p.h[9] = lx; p.h[10] = ly; p.h[11] = lz;
    p.h[12] = (f16)1.f; p.h[13] = (f16)1.f; p.h[14] = (f16)0.f; p.h[15] = (f16)0.f;
    return p;
}

// Pack A/B fragment arrays ONCE (removes 64x-redundant per-block pack VALU).
__global__ __launch_bounds__(BLOCK) void chamfer_prep(
    const float* __restrict__ Xc, const float* __restrict__ Xt,
    uint4* __restrict__ Ac, uint4* __restrict__ At,
    uint4* __restrict__ Bc, uint4* __restrict__ Bt,
    float* __restrict__ out)
{
    int i = blockIdx.x * BLOCK + threadIdx.x;
    if (i == 0) out[0] = 0.0f;   // stream-ordered before reduce's atomicAdd
    float x = Xc[3 * i], y = Xc[3 * i + 1], z = Xc[3 * i + 2];
    Pack a = pack_q(x, y, z), b = pack_db(x, y, z);
    Ac[2 * i] = a.u[0]; Ac[2 * i + 1] = a.u[1];
    Bc[2 * i] = b.u[0]; Bc[2 * i + 1] = b.u[1];
    x = Xt[3 * i]; y = Xt[3 * i + 1]; z = Xt[3 * i + 2];
    a = pack_q(x, y, z); b = pack_db(x, y, z);
    At[2 * i] = a.u[0]; At[2 * i + 1] = a.u[1];
    Bt[2 * i] = b.u[0]; Bt[2 * i + 1] = b.u[1];
}

// XOR-swizzle on 16B-granule index (involution, within 1KB / one bt-group):
// spreads the read's bank quads so each 8-lane service group hits 8 distinct
// quads. Applied to the global SOURCE of global_load_lds (LDS dest stays
// linear, rule 21) and to the LDS read address.
__device__ __forceinline__ int swz(int g) { return g ^ ((g >> 3) & 7); }

__global__ __launch_bounds__(BLOCK) void chamfer_pass(
    const uint4* __restrict__ Ac, const uint4* __restrict__ At,
    const uint4* __restrict__ Bc, const uint4* __restrict__ Bt,
    float* __restrict__ part)
{
    __shared__ uint4 tile[2 * STAGEPTS * 2];   // 2 buffers x 16 KB = 32 KB

    const int tid  = threadIdx.x;
    const int lane = tid & 63;
    const int w    = tid >> 6;
    const int col  = lane & 31;   // A row / B col within a 32x32 tile
    const int ksel = lane >> 5;   // K-half selector

    const uint4* Aq = blockIdx.z ? At : Ac;
    const char*  Bd = (const char*)(blockIdx.z ? Bc : Bt);

    // ---- 4 A-tiles (128 queries) per wave, coalesced b128 loads ----
    const int qw = blockIdx.x * (4 * QPW) + w * QPW;
    f16x8 a[4];
#pragma unroll
    for (int t = 0; t < 4; ++t) {
        U8 u; u.u = Aq[(qw + t * 32 + col) * 2 + ksel];
        a[t] = u.v;
    }

    f32x16 acc[4], zacc;
#pragma unroll
    for (int r = 0; r < 16; ++r) zacc[r] = 0.f;
#pragma unroll
    for (int t = 0; t < 4; ++t)
#pragma unroll
        for (int r = 0; r < 16; ++r) acc[t][r] = 3.0e38f;

    const char* chunkbase = Bd + (size_t)blockIdx.y * (CHUNKPTS * 32);
    const int   srcperm   = swz(lane) * 16;          // per-lane swizzled source
    char*       ldsbase   = (char*)tile;

    // per-lane LDS read offset inside one bt-group (64 granules = 1 KB)
    const int glow   = col * 2 + ksel;
    const int ldsoff = swz(glow) * 16;

    // stage sidx (16 KB) into buffer bufsel: 4 x global_load_lds(16B) per thread
#define STAGE(sidx, bufsel)                                                    \
    {                                                                          \
        const char* src_ = chunkbase + (sidx) * STAGEBYTES + w * 4096 + srcperm; \
        char*       dst_ = ldsbase + (bufsel) * STAGEBYTES + w * 4096;         \
        _Pragma("unroll")                                                      \
        for (int i_ = 0; i_ < 4; ++i_)                                         \
            __builtin_amdgcn_global_load_lds(                                  \
                (const __attribute__((address_space(1))) void*)(src_ + i_ * 1024), \
                (__attribute__((address_space(3))) void*)(dst_ + i_ * 1024),   \
                16, 0, 0);                                                     \
    }

    STAGE(0, 0);

    const char* rdbase = ldsbase + ldsoff;
#pragma unroll
    for (int s = 0; s < NSTAGE; ++s) {
        if (s + 1 < NSTAGE) {
            STAGE(s + 1, (s + 1) & 1);
            // my stage-s loads done; keep stage-(s+1)'s 4 loads in flight
            asm volatile("s_waitcnt vmcnt(4)" ::: "memory");
        } else {
            asm volatile("s_waitcnt vmcnt(0)" ::: "memory");
        }
        __builtin_amdgcn_s_barrier();          // all waves' stage-s data landed
        asm volatile("" ::: "memory");

        const char* rb = rdbase + (s & 1) * STAGEBYTES;
#pragma unroll
        for (int bt = 0; bt < 16; bt += 2) {
            U8 u0, u1;
            u0.u = *(const uint4*)(rb + bt * 1024);
            u1.u = *(const uint4*)(rb + bt * 1024 + 1024);
            f16x8 b0 = u0.v, b1 = u1.v;
#pragma unroll
            for (int t = 0; t < 4; ++t) {
                f32x16 d0 = __builtin_amdgcn_mfma_f32_32x32x16_f16(a[t], b0, zacc, 0, 0, 0);
                f32x16 d1 = __builtin_amdgcn_mfma_f32_32x32x16_f16(a[t], b1, zacc, 0, 0, 0);
#pragma unroll
                for (int r = 0; r < 16; ++r)   // v_min3_f32
                    acc[t][r] = fminf(fminf(d0[r], d1[r]), acc[t][r]);
            }
        }
        asm volatile("" ::: "memory");
        __builtin_amdgcn_s_barrier();          // reads done before buf reuse
    }

    // ---- min over the 32 db-columns; store per-chunk partials ----
#pragma unroll
    for (int t = 0; t < 4; ++t) {
#pragma unroll
        for (int r = 0; r < 16; ++r) {
            float v = acc[t][r];
#pragma unroll
            for (int off = 1; off < 32; off <<= 1)
                v = fminf(v, __shfl_xor(v, off, 64));
            if (col == 0) {
                // C/D layout (HW-verified): col=lane&31, row=(r&3)+8*(r>>2)+4*ksel
                int row = (r & 3) + 8 * (r >> 2) + 4 * ksel;
                int q   = qw + t * 32 + row;
                part[((size_t)blockIdx.z * NQ + q) * DC + blockIdx.y] = v;
            }
        }
    }
#undef STAGE
}

// 8-way min over chunks, add |q|^2 (recomputed from raw input), clamp, average.
__global__ __launch_bounds__(BLOCK) void chamfer_reduce(
    const float* __restrict__ part, const float* __restrict__ Xc,
    const float* __restrict__ Xt, float* __restrict__ out)
{
    __shared__ float red[4];
    int e = blockIdx.x * BLOCK + threadIdx.x;   // 0 .. 2*NQ-1

    const float4* pb = (const float4*)(part + (size_t)e * DC);
    float4 m0 = pb[0], m1 = pb[1];
    float mn = fminf(fminf(fminf(m0.x, m0.y), fminf(m0.z, m0.w)),
                     fminf(fminf(m1.x, m1.y), fminf(m1.z, m1.w)));

    const float* X = (e < NQ) ? Xc : Xt;
    int q = (e < NQ) ? e : e - NQ;
    float x = X[3 * q], y = X[3 * q + 1], z = X[3 * q + 2];
    float n2 = fmaf(x, x, fmaf(y, y, z * z));
    float s = fmaxf(mn + n2, 0.0f) * (1.0f / 16384.0f);

#pragma unroll
    for (int off = 32; off > 0; off >>= 1) s += __shfl_down(s, off, 64);
    int wv = threadIdx.x >> 6, ln = threadIdx.x & 63;
    if (ln == 0) red[wv] = s;
    __syncthreads();
    if (threadIdx.x == 0) atomicAdd(out, red[0] + red[1] + red[2] + red[3]);
}

extern "C" void kernel_launch(void* const* d_in, const int* in_sizes, int n_in,
                              void* d_out, int out_size, void* d_ws, size_t ws_size,
                              hipStream_t stream) {
    const float* Xc = (const float*)d_in[0];
    const float* Xt = (const float*)d_in[1];
    float* out = (float*)d_out;

    // ws: Ac | At | Bc | Bt (each 16384*32B = 512KB) | part (2*16384*8 f32 = 1MB)
    uint4* Ac = (uint4*)d_ws;
    uint4* At = Ac + 2 * NQ;
    uint4* Bc = At + 2 * NQ;
    uint4* Bt = Bc + 2 * NQ;
    float* part = (float*)(Bt + 2 * NQ);

    chamfer_prep<<<NQ / BLOCK, BLOCK, 0, stream>>>(Xc, Xt, Ac, At, Bc, Bt, out);

    dim3 grid(NQ / (4 * QPW) /*32*/, DC, 2);   // 512 blocks, 4 waves each
    chamfer_pass<<<grid, BLOCK, 0, stream>>>(Ac, At, Bc, Bt, part);

    chamfer_reduce<<<(2 * NQ) / BLOCK, BLOCK, 0, stream>>>(part, Xc, Xt, out);
}

// Round 5
// 90.778 us; speedup vs baseline: 45.4765x; 45.4765x over previous
//
#include <hip/hip_runtime.h>

#define BLOCK    256
#define DC       8          // db chunks (grid.y)
#define CHUNKPTS 2048       // db points per block-chunk
#define NQ       16384

typedef _Float16 f16;
typedef __attribute__((ext_vector_type(8)))  _Float16 f16x8;
typedef __attribute__((ext_vector_type(16))) float    f32x16;

union Pack { f16 h[16]; uint4 u[2]; };
union U8   { uint4 u; f16x8 v; };

__device__ __forceinline__ void split(float v, f16& h, f16& l) {
    h = (f16)v;
    l = (f16)(v - (float)h);
}

// db-side K-row: B[k] = {ph(3), pl(3), ph(3), pl(3), n2h, n2l, 0, 0}
__device__ __forceinline__ Pack pack_db(float x, float y, float z) {
    f16 hx, lx, hy, ly, hz, lz, nh, nl;
    split(x, hx, lx); split(y, hy, ly); split(z, hz, lz);
    float n2 = fmaf(x, x, fmaf(y, y, z * z));
    split(n2, nh, nl);
    Pack p;
    p.h[0] = hx;  p.h[1] = hy;  p.h[2] = hz;
    p.h[3] = lx;  p.h[4] = ly;  p.h[5] = lz;
    p.h[6] = hx;  p.h[7] = hy;  p.h[8] = hz;
    p.h[9] = lx;  p.h[10] = ly; p.h[11] = lz;
    p.h[12] = nh; p.h[13] = nl; p.h[14] = (f16)0.f; p.h[15] = (f16)0.f;
    return p;
}

// query-side K-row: A[k] = {-2qh(3), -2qh(3), -2ql(3), -2ql(3), 1, 1, 0, 0}
// pairing with B gives  -2*(qh+ql).(ph+pl) + |p|^2  to ~2^-22 relative.
__device__ __forceinline__ Pack pack_q(float x, float y, float z) {
    f16 hx, lx, hy, ly, hz, lz;
    split(-2.f * x, hx, lx); split(-2.f * y, hy, ly); split(-2.f * z, hz, lz);
    Pack p;
    p.h[0] = hx; p.h[1] = hy; p.h[2] = hz;
    p.h[3] = hx; p.h[4] = hy; p.h[5] = hz;
    p.h[6] = lx; p.h[7] = ly; p.h[8] = lz;
    p.h[9] = lx; p.h[10] = ly; p.h[11] = lz;
    p.h[12] = (f16)1.f; p.h[13] = (f16)1.f; p.h[14] = (f16)0.f; p.h[15] = (f16)0.f;
    return p;
}

// Pack A/B fragment arrays ONCE. Removes all per-block pack VALU from the pass.
__global__ __launch_bounds__(BLOCK) void chamfer_prep(
    const float* __restrict__ Xc, const float* __restrict__ Xt,
    uint4* __restrict__ Ac, uint4* __restrict__ At,
    uint4* __restrict__ Bc, uint4* __restrict__ Bt,
    float* __restrict__ out)
{
    int i = blockIdx.x * BLOCK + threadIdx.x;
    if (i == 0) out[0] = 0.0f;   // stream-ordered before reduce's atomicAdd
    float x = Xc[3 * i], y = Xc[3 * i + 1], z = Xc[3 * i + 2];
    Pack a = pack_q(x, y, z), b = pack_db(x, y, z);
    Ac[2 * i] = a.u[0]; Ac[2 * i + 1] = a.u[1];
    Bc[2 * i] = b.u[0]; Bc[2 * i + 1] = b.u[1];
    x = Xt[3 * i]; y = Xt[3 * i + 1]; z = Xt[3 * i + 2];
    a = pack_q(x, y, z); b = pack_db(x, y, z);
    At[2 * i] = a.u[0]; At[2 * i + 1] = a.u[1];
    Bt[2 * i] = b.u[0]; Bt[2 * i + 1] = b.u[1];
}

// No LDS: B (512 KB/dir, prep-packed) is L2-resident; each wave streams its
// chunk straight into B fragments (1 coalesced dwordx4 per 32-pt group/lane).
// acc stays at 2 tiles -- the round-3 4-tile variant spilled (VGPR 252, 14 GB
// scratch traffic); 2 tiles measured at 48 VGPR.
__global__ __launch_bounds__(BLOCK) void chamfer_pass(
    const uint4* __restrict__ Ac, const uint4* __restrict__ At,
    const uint4* __restrict__ Bc, const uint4* __restrict__ Bt,
    float* __restrict__ part)
{
    const int tid  = threadIdx.x;
    const int lane = tid & 63;
    const int w    = tid >> 6;
    const int col  = lane & 31;   // A row / B col within a 32x32 tile
    const int ksel = lane >> 5;   // K-half selector

    const uint4* Aq = blockIdx.z ? At : Ac;
    const uint4* Bd = blockIdx.z ? Bc : Bt;

    // ---- 2 A-tiles (64 queries) per wave ----
    const int qw = blockIdx.x * BLOCK + w * 64;
    f16x8 a0, a1;
    {
        U8 u;
        u.u = Aq[(qw + col) * 2 + ksel];      a0 = u.v;
        u.u = Aq[(qw + 32 + col) * 2 + ksel]; a1 = u.v;
    }

    f32x16 acc0, acc1, zacc;
#pragma unroll
    for (int r = 0; r < 16; ++r) { acc0[r] = 3.0e38f; acc1[r] = 3.0e38f; zacc[r] = 0.f; }

    // chunk = 2048 pts = 64 groups of 32 pts; one 1 KB group = one full
    // 32-col x K=16 B-tile. Per-lane granule offset inside a group: col*2+ksel.
    const uint4* bbase = Bd + (size_t)blockIdx.y * (CHUNKPTS * 2) + (col * 2 + ksel);

#pragma unroll 4
    for (int g = 0; g < 64; g += 2) {
        U8 u0, u1;
        u0.u = bbase[(g    ) * 64];
        u1.u = bbase[(g + 1) * 64];
        f16x8 b0 = u0.v, b1 = u1.v;
        f32x16 d0 = __builtin_amdgcn_mfma_f32_32x32x16_f16(a0, b0, zacc, 0, 0, 0);
        f32x16 d1 = __builtin_amdgcn_mfma_f32_32x32x16_f16(a0, b1, zacc, 0, 0, 0);
#pragma unroll
        for (int r = 0; r < 16; ++r)   // v_min3_f32
            acc0[r] = fminf(fminf(d0[r], d1[r]), acc0[r]);
        f32x16 e0 = __builtin_amdgcn_mfma_f32_32x32x16_f16(a1, b0, zacc, 0, 0, 0);
        f32x16 e1 = __builtin_amdgcn_mfma_f32_32x32x16_f16(a1, b1, zacc, 0, 0, 0);
#pragma unroll
        for (int r = 0; r < 16; ++r)
            acc1[r] = fminf(fminf(e0[r], e1[r]), acc1[r]);
    }

    // ---- min over the 32 db-columns (xor<=16 stays inside each half-wave) ----
#pragma unroll
    for (int r = 0; r < 16; ++r) {
        float v0 = acc0[r], v1 = acc1[r];
#pragma unroll
        for (int off = 1; off < 32; off <<= 1) {
            v0 = fminf(v0, __shfl_xor(v0, off, 64));
            v1 = fminf(v1, __shfl_xor(v1, off, 64));
        }
        if (col == 0) {
            // C/D layout (HW-verified): col=lane&31, row=(r&3)+8*(r>>2)+4*ksel
            int row = (r & 3) + 8 * (r >> 2) + 4 * ksel;
            int q0  = qw + row;
            part[((size_t)blockIdx.z * NQ + q0) * DC + blockIdx.y]      = v0;
            part[((size_t)blockIdx.z * NQ + q0 + 32) * DC + blockIdx.y] = v1;
        }
    }
}

// 8-way min over chunks, add |q|^2 (recomputed from raw input), clamp, average.
__global__ __launch_bounds__(BLOCK) void chamfer_reduce(
    const float* __restrict__ part, const float* __restrict__ Xc,
    const float* __restrict__ Xt, float* __restrict__ out)
{
    __shared__ float red[4];
    int e = blockIdx.x * BLOCK + threadIdx.x;   // 0 .. 2*NQ-1

    const float4* pb = (const float4*)(part + (size_t)e * DC);
    float4 m0 = pb[0], m1 = pb[1];
    float mn = fminf(fminf(fminf(m0.x, m0.y), fminf(m0.z, m0.w)),
                     fminf(fminf(m1.x, m1.y), fminf(m1.z, m1.w)));

    const float* X = (e < NQ) ? Xc : Xt;
    int q = (e < NQ) ? e : e - NQ;
    float x = X[3 * q], y = X[3 * q + 1], z = X[3 * q + 2];
    float n2 = fmaf(x, x, fmaf(y, y, z * z));
    float s = fmaxf(mn + n2, 0.0f) * (1.0f / 16384.0f);

#pragma unroll
    for (int off = 32; off > 0; off >>= 1) s += __shfl_down(s, off, 64);
    int wv = threadIdx.x >> 6, ln = threadIdx.x & 63;
    if (ln == 0) red[wv] = s;
    __syncthreads();
    if (threadIdx.x == 0) atomicAdd(out, red[0] + red[1] + red[2] + red[3]);
}

extern "C" void kernel_launch(void* const* d_in, const int* in_sizes, int n_in,
                              void* d_out, int out_size, void* d_ws, size_t ws_size,
                              hipStream_t stream) {
    const float* Xc = (const float*)d_in[0];
    const float* Xt = (const float*)d_in[1];
    float* out = (float*)d_out;

    // ws: Ac | At | Bc | Bt (each 16384*32B = 512KB) | part (2*16384*8 f32 = 1MB)
    uint4* Ac = (uint4*)d_ws;
    uint4* At = Ac + 2 * NQ;
    uint4* Bc = At + 2 * NQ;
    uint4* Bt = Bc + 2 * NQ;
    float* part = (float*)(Bt + 2 * NQ);

    chamfer_prep<<<NQ / BLOCK, BLOCK, 0, stream>>>(Xc, Xt, Ac, At, Bc, Bt, out);

    dim3 grid(NQ / BLOCK /*64*/, DC, 2);   // 1024 blocks, 4 waves each
    chamfer_pass<<<grid, BLOCK, 0, stream>>>(Ac, At, Bc, Bt, part);

    chamfer_reduce<<<(2 * NQ) / BLOCK, BLOCK, 0, stream>>>(part, Xc, Xt, out);
}